// Round 1
// baseline (405.916 us; speedup 1.0000x reference)
//
#include <hip/hip_runtime.h>
#include <hip/hip_bf16.h>

// Problem: B=8, H=W=128, C=F=256, 3x3 modulated conv (StyleGAN2 style).
// Strategy: bf16 MFMA implicit GEMM. out[b,h,w,f] = sum_{t,c} x[b,h',w',c]*wmod[b,t,c,f]

#define NB 8
#define NH 128
#define NW 128
#define NC 256
#define NF 256

typedef __attribute__((ext_vector_type(8))) short bf16x8;
typedef __attribute__((ext_vector_type(4))) float f32x4;

// ---------------- x fp32 -> bf16 ----------------
__global__ void k_cvt(const float* __restrict__ x, ushort* __restrict__ xbf) {
    int i = (blockIdx.x * blockDim.x + threadIdx.x) * 4;
    float4 v = *(const float4*)(x + i);
    union { ushort4 u; __hip_bfloat16 h[4]; } o;
    o.h[0] = __float2bfloat16(v.x);
    o.h[1] = __float2bfloat16(v.y);
    o.h[2] = __float2bfloat16(v.z);
    o.h[3] = __float2bfloat16(v.w);
    *(ushort4*)(xbf + i) = o.u;
}

// ---------------- modulate + demodulate weights ----------------
// One block per (b,f), 256 threads (one per c).
// Writes wm layout [b][tap][f][c]  (c contiguous) as bf16.
__global__ void k_modw(const float* __restrict__ kern, const float* __restrict__ style,
                       ushort* __restrict__ wm) {
    int b = blockIdx.x >> 8;
    int f = blockIdx.x & 255;
    int c = threadIdx.x;
    float s = style[b * 256 + c] + 1.0f;
    float w[9];
    float acc = 0.f;
#pragma unroll
    for (int t = 0; t < 9; ++t) {
        w[t] = kern[(t * 256 + c) * 256 + f] * s;
        acc += w[t] * w[t];
    }
    // block reduction (wave shuffle + LDS across 4 waves)
#pragma unroll
    for (int off = 32; off; off >>= 1) acc += __shfl_down(acc, off);
    __shared__ float part[4];
    if ((threadIdx.x & 63) == 0) part[threadIdx.x >> 6] = acc;
    __syncthreads();
    float total = part[0] + part[1] + part[2] + part[3];
    float inv = 1.0f / sqrtf(total + 1e-8f);
#pragma unroll
    for (int t = 0; t < 9; ++t) {
        union { ushort u; __hip_bfloat16 h; } o;
        o.h = __float2bfloat16(w[t] * inv);
        wm[(((b * 9 + t) * 256 + f) * 256) + c] = o.u;
    }
}

// ---------------- conv as implicit GEMM ----------------
// Block = (b, h, f_half). M-tile = 128 (one full image row of w), N-tile = 128 (half of F).
// K loop: 8 chunks of 32 c; per chunk stage 3 x-rows (with +-1 w halo) into LDS,
// then 9 taps: stage B chunk [128 f][32 c], 16 MFMA per wave.
__global__ void __launch_bounds__(256)
k_conv(const ushort* __restrict__ xbf, const ushort* __restrict__ wm,
       float* __restrict__ out) {
    const int bidx = blockIdx.x;
    const int fh = bidx & 1;
    const int h  = (bidx >> 1) & 127;
    const int b  = bidx >> 8;

    __shared__ ushort As[3][130 * 32];  // [dh][(w+1)*32 + c], w in [-1,128]
    __shared__ ushort Bs[128 * 32];     // [f_local*32 + c]

    const int tid = threadIdx.x;
    const int wave = tid >> 6, lane = tid & 63;
    const int wm_ = wave & 1, wn_ = wave >> 1;   // 2x2 wave grid, each 64x64
    const int lrow = lane & 15;
    const int quad = lane >> 4;

    // Zero halo columns (w=-1 and w=128) for all rows, all c — constant across chunks.
    for (int i = tid; i < 3 * 2 * 32; i += 256) {
        int dh = i >> 6;
        int side = (i >> 5) & 1;
        int cc = i & 31;
        As[dh][(side ? 129 : 0) * 32 + cc] = 0;
    }
    // Zero rows that fall outside the image (constant across chunks).
#pragma unroll
    for (int dh = 0; dh < 3; ++dh) {
        int hp = h + dh - 1;
        if (hp < 0 || hp >= 128) {
            for (int i = tid; i < 130 * 32; i += 256) As[dh][i] = 0;
        }
    }

    f32x4 acc[4][4];
    const f32x4 zero4 = {0.f, 0.f, 0.f, 0.f};
#pragma unroll
    for (int mi = 0; mi < 4; ++mi)
#pragma unroll
        for (int ni = 0; ni < 4; ++ni) acc[mi][ni] = zero4;

    const int wload = tid >> 2;          // 0..63
    const int cload = (tid & 3) * 8;     // 0,8,16,24

    for (int c0 = 0; c0 < 256; c0 += 32) {
        __syncthreads();  // previous chunk's A reads complete
        // ---- stage A: 3 rows x 128 w x 32 c (interior only; halo stays 0) ----
#pragma unroll
        for (int dh = 0; dh < 3; ++dh) {
            int hp = h + dh - 1;
            if (hp >= 0 && hp < 128) {
                const ushort* src = xbf + ((b * 128 + hp) * 128) * 256 + c0;
#pragma unroll
                for (int j = 0; j < 2; ++j) {
                    int w = j * 64 + wload;
                    uint4 v = *(const uint4*)(src + w * 256 + cload);
                    *(uint4*)&As[dh][(w + 1) * 32 + cload] = v;
                }
            }
        }
#pragma unroll
        for (int dh = 0; dh < 3; ++dh) {
#pragma unroll
            for (int dw = 0; dw < 3; ++dw) {
                const int tap = dh * 3 + dw;
                __syncthreads();  // prior tap's B reads done (first iter: A staged)
                // ---- stage B: 128 f x 32 c ----
                {
                    const ushort* src = wm + ((b * 9 + tap) * 256 + fh * 128) * 256 + c0;
#pragma unroll
                    for (int j = 0; j < 2; ++j) {
                        int fl = j * 64 + wload;
                        uint4 v = *(const uint4*)(src + fl * 256 + cload);
                        *(uint4*)&Bs[fl * 32 + cload] = v;
                    }
                }
                __syncthreads();
                // ---- fragments + MFMA ----
                bf16x8 af[4], bfr[4];
#pragma unroll
                for (int ni = 0; ni < 4; ++ni) {
                    int fl = wn_ * 64 + ni * 16 + lrow;
                    bfr[ni] = *(const bf16x8*)&Bs[fl * 32 + quad * 8];
                }
#pragma unroll
                for (int mi = 0; mi < 4; ++mi) {
                    int w = wm_ * 64 + mi * 16 + lrow;
                    af[mi] = *(const bf16x8*)&As[dh][(w + dw) * 32 + quad * 8];
                }
#pragma unroll
                for (int mi = 0; mi < 4; ++mi)
#pragma unroll
                    for (int ni = 0; ni < 4; ++ni)
                        acc[mi][ni] = __builtin_amdgcn_mfma_f32_16x16x32_bf16(
                            af[mi], bfr[ni], acc[mi][ni], 0, 0, 0);
            }
        }
    }

    // ---- epilogue: C/D layout col=lane&15, row=quad*4+reg ----
    float* obase = out + ((b * 128 + h) * 128) * 256 + fh * 128;
#pragma unroll
    for (int mi = 0; mi < 4; ++mi) {
        int wrow = wm_ * 64 + mi * 16 + quad * 4;
#pragma unroll
        for (int ni = 0; ni < 4; ++ni) {
            int f = wn_ * 64 + ni * 16 + lrow;
            f32x4 v = acc[mi][ni];
#pragma unroll
            for (int r = 0; r < 4; ++r) {
                obase[(wrow + r) * 256 + f] = v[r];
            }
        }
    }
}

extern "C" void kernel_launch(void* const* d_in, const int* in_sizes, int n_in,
                              void* d_out, int out_size, void* d_ws, size_t ws_size,
                              hipStream_t stream) {
    const float* x     = (const float*)d_in[0];   // [8,128,128,256]
    const float* style = (const float*)d_in[1];   // [8,1,1,256]
    const float* kern  = (const float*)d_in[2];   // [3,3,256,256]
    float* out = (float*)d_out;                   // [8,128,128,256]

    ushort* xbf = (ushort*)d_ws;                  // 33,554,432 bf16 = 64 MiB
    ushort* wmod = xbf + (size_t)NB * NH * NW * NC;  // 8*9*256*256 bf16 = 9 MiB

    // x -> bf16
    k_cvt<<<(NB * NH * NW * NC) / (256 * 4), 256, 0, stream>>>(x, xbf);
    // modulated/demodulated weights -> bf16, [b][tap][f][c]
    k_modw<<<NB * NF, 256, 0, stream>>>(kern, style, wmod);
    // conv
    k_conv<<<NB * NH * 2, 256, 0, stream>>>(xbf, wmod, out);
}